// Round 4
// baseline (153.772 us; speedup 1.0000x reference)
//
#include <hip/hip_runtime.h>
#include <hip/hip_bf16.h>

#define OUTF 4096
#define INF  4096
#define BATCH 128
#define NB 256         // localsort blocks (private chunks) — 1 per CU
#define SORT_T 512     // threads per localsort block

// ---- generic 32x32 tiled transpose: in[R][C] -> out[C][R] (R,C % 32 == 0) ----
__global__ __launch_bounds__(1024) void k_transpose32(const float* __restrict__ in,
                                                      float* __restrict__ out,
                                                      int R, int C) {
  __shared__ float t[32][33];
  int bx = blockIdx.x * 32, by = blockIdx.y * 32;
  t[threadIdx.y][threadIdx.x] = in[(size_t)(by + threadIdx.y) * C + (bx + threadIdx.x)];
  __syncthreads();
  out[(size_t)(bx + threadIdx.y) * R + (by + threadIdx.x)] = t[threadIdx.x][threadIdx.y];
}

// ---- block-local counting sort into private contiguous range (no bounce) ----
__global__ __launch_bounds__(SORT_T) void k_localsort(
    const float* __restrict__ vals, const int* __restrict__ rows,
    const int* __restrict__ cols, int nnz, int chunk,
    int2* __restrict__ svc, int* __restrict__ segStart) {
  __shared__ int hist[OUTF];      // 16 KB
  __shared__ int cursor[OUTF];    // 16 KB
  __shared__ int scanTmp[SORT_T];
  const int blk = blockIdx.x;
  const int t = threadIdx.x;
  const int s = blk * chunk;
  const int e = min(nnz, s + chunk);

  for (int i = t; i < OUTF; i += SORT_T) hist[i] = 0;
  __syncthreads();
  for (int i = s + t; i < e; i += SORT_T)
    atomicAdd(&hist[rows[i]], 1);
  __syncthreads();

  const int BINS = OUTF / SORT_T;  // 8
  int base = t * BINS;
  int loc[BINS];
  int sum = 0;
#pragma unroll
  for (int j = 0; j < BINS; ++j) { loc[j] = sum; sum += hist[base + j]; }
  scanTmp[t] = sum;
  __syncthreads();
  for (int off = 1; off < SORT_T; off <<= 1) {
    int v = (t >= off) ? scanTmp[t - off] : 0;
    __syncthreads();
    scanTmp[t] += v;
    __syncthreads();
  }
  int excl = scanTmp[t] - sum;
#pragma unroll
  for (int j = 0; j < BINS; ++j) {
    int abs_start = s + excl + loc[j];
    segStart[blk * (OUTF + 1) + base + j] = abs_start;
    cursor[base + j] = abs_start;
  }
  if (t == 0) segStart[blk * (OUTF + 1) + OUTF] = e;
  __syncthreads();

  for (int i = s + t; i < e; i += SORT_T) {
    int r = rows[i];
    int p = atomicAdd(&cursor[r], 1);
    int2 vc;
    vc.x = __float_as_int(vals[i]);
    vc.y = cols[i];
    svc[p] = vc;
  }
}

// ---- per-row total counts across NB blocks (coalesced in r) ----
__global__ __launch_bounds__(256) void k_counts(const int* __restrict__ segStart,
                                                int* __restrict__ count) {
  int r = blockIdx.x * 256 + threadIdx.x;
  int c = 0;
  for (int b = 0; b < NB; ++b) {
    const int* sp = segStart + b * (OUTF + 1) + r;
    c += sp[1] - sp[0];
  }
  count[r] = c;
}

// ---- exclusive scan of count[4096] -> rowPtr[4097] ----
__global__ __launch_bounds__(1024) void k_scan(const int* __restrict__ counts,
                                               int* __restrict__ rowPtr) {
  __shared__ int tot[1024];
  int t = threadIdx.x;
  int4 c = ((const int4*)counts)[t];
  int mySum = c.x + c.y + c.z + c.w;
  tot[t] = mySum;
  __syncthreads();
  for (int off = 1; off < 1024; off <<= 1) {
    int v = (t >= off) ? tot[t - off] : 0;
    __syncthreads();
    tot[t] += v;
    __syncthreads();
  }
  int excl = tot[t] - mySum;
  int4 rs;
  rs.x = excl;
  rs.y = excl + c.x;
  rs.z = excl + c.x + c.y;
  rs.w = excl + c.x + c.y + c.z;
  ((int4*)rowPtr)[t] = rs;
  if (t == 1023) rowPtr[4096] = tot[1023];
}

// ---- repack: gather each row's NB segments into one contiguous csr range ----
__global__ __launch_bounds__(64) void k_repack(const int2* __restrict__ svc,
                                               const int* __restrict__ segStart,
                                               const int* __restrict__ rowPtr,
                                               int2* __restrict__ csr) {
  const int r = blockIdx.x;
  const int lane = threadIdx.x;
  const int NT = NB / 64;  // 4 segments per lane
  int sseg[NT], len[NT];
  int tot = 0;
#pragma unroll
  for (int t = 0; t < NT; ++t) {
    int base = (t * 64 + lane) * (OUTF + 1) + r;
    int s0 = segStart[base];
    int e0 = segStart[base + 1];
    sseg[t] = s0;
    len[t] = e0 - s0;
    tot += len[t];
  }
  int v = tot;
#pragma unroll
  for (int off = 1; off < 64; off <<= 1) {
    int u = __shfl_up(v, off);
    if (lane >= off) v += u;
  }
  int dst = rowPtr[r] + v - tot;
#pragma unroll
  for (int t = 0; t < NT; ++t) {
    for (int k = 0; k < len[t]; ++k) csr[dst + k] = svc[sseg[t] + k];
    dst += len[t];
  }
}

// ---- CSR SpMM: wave per row, 8-wide batches, 2-deep software pipeline ----
// Entry batches are wave-uniform (s_load_dwordx16), kept 2 batches ahead;
// XT gathers 1 batch ahead; 8 independent accumulators.
__global__ __launch_bounds__(64) void k_spmm(const int2* __restrict__ csr,
                                             const int* __restrict__ rowPtr,
                                             const float* __restrict__ XT,
                                             float* __restrict__ outT) {
  const int r = blockIdx.x;
  const int lane = threadIdx.x;
  const float2* __restrict__ XT2 = (const float2*)XT;
  const int s = rowPtr[r];
  const int e = rowPtr[r + 1];
  const int nb = (e - s) >> 3;

  float2 acc[8];
#pragma unroll
  for (int j = 0; j < 8; ++j) acc[j] = make_float2(0.f, 0.f);

  int2 EA[8], EB[8];
  float2 XA[8], XB[8];

  if (nb >= 1) {
#pragma unroll
    for (int j = 0; j < 8; ++j) EA[j] = csr[s + j];
  }
  if (nb >= 2) {
#pragma unroll
    for (int j = 0; j < 8; ++j) EB[j] = csr[s + 8 + j];
  }
  if (nb >= 1) {
#pragma unroll
    for (int j = 0; j < 8; ++j) XA[j] = XT2[EA[j].y * 64 + lane];
  }

  int k = 0;
  for (; k + 2 < nb; k += 2) {
    // even phase: gather batch k+1, compute batch k, load batch k+2
#pragma unroll
    for (int j = 0; j < 8; ++j) XB[j] = XT2[EB[j].y * 64 + lane];
#pragma unroll
    for (int j = 0; j < 8; ++j) {
      float v0 = __int_as_float(EA[j].x);
      acc[j].x = fmaf(v0, XA[j].x, acc[j].x);
      acc[j].y = fmaf(v0, XA[j].y, acc[j].y);
    }
#pragma unroll
    for (int j = 0; j < 8; ++j) EA[j] = csr[s + (k + 2) * 8 + j];
    // odd phase: gather batch k+2, compute batch k+1, load batch k+3
#pragma unroll
    for (int j = 0; j < 8; ++j) XA[j] = XT2[EA[j].y * 64 + lane];
#pragma unroll
    for (int j = 0; j < 8; ++j) {
      float v0 = __int_as_float(EB[j].x);
      acc[j].x = fmaf(v0, XB[j].x, acc[j].x);
      acc[j].y = fmaf(v0, XB[j].y, acc[j].y);
    }
    if (k + 3 < nb) {
#pragma unroll
      for (int j = 0; j < 8; ++j) EB[j] = csr[s + (k + 3) * 8 + j];
    }
  }
  // drain: batch k (in EA/XA, gathered), then optional batch k+1 (in EB)
  if (k < nb) {
#pragma unroll
    for (int j = 0; j < 8; ++j) {
      float v0 = __int_as_float(EA[j].x);
      acc[j].x = fmaf(v0, XA[j].x, acc[j].x);
      acc[j].y = fmaf(v0, XA[j].y, acc[j].y);
    }
    ++k;
    if (k < nb) {
#pragma unroll
      for (int j = 0; j < 8; ++j) XB[j] = XT2[EB[j].y * 64 + lane];
#pragma unroll
      for (int j = 0; j < 8; ++j) {
        float v0 = __int_as_float(EB[j].x);
        acc[j].x = fmaf(v0, XB[j].x, acc[j].x);
        acc[j].y = fmaf(v0, XB[j].y, acc[j].y);
      }
      ++k;
    }
  }
  // tail entries (< 8)
  for (int p = s + nb * 8; p < e; ++p) {
    int2 t = csr[p];
    float2 x = XT2[t.y * 64 + lane];
    float v0 = __int_as_float(t.x);
    acc[0].x = fmaf(v0, x.x, acc[0].x);
    acc[0].y = fmaf(v0, x.y, acc[0].y);
  }
  float2 res;
  res.x = ((acc[0].x + acc[1].x) + (acc[2].x + acc[3].x)) +
          ((acc[4].x + acc[5].x) + (acc[6].x + acc[7].x));
  res.y = ((acc[0].y + acc[1].y) + (acc[2].y + acc[3].y)) +
          ((acc[4].y + acc[5].y) + (acc[6].y + acc[7].y));
  ((float2*)outT)[r * 64 + lane] = res;
}

// ---- safety-net fallback if ws is too small: direct atomics ----
__global__ __launch_bounds__(256) void k_fallback(const float* __restrict__ X,
                                                  const float* __restrict__ vals,
                                                  const int* __restrict__ rows,
                                                  const int* __restrict__ cols, int n,
                                                  float* __restrict__ out) {
  int k = blockIdx.x * blockDim.x + threadIdx.x;
  if (k >= n) return;
  float v = vals[k];
  int r = rows[k], c = cols[k];
  for (int b = 0; b < BATCH; ++b)
    atomicAdd(&out[(size_t)b * OUTF + r], v * X[(size_t)b * INF + c]);
}

extern "C" void kernel_launch(void* const* d_in, const int* in_sizes, int n_in,
                              void* d_out, int out_size, void* d_ws, size_t ws_size,
                              hipStream_t stream) {
  const float* X  = (const float*)d_in[0];
  const float* Wv = (const float*)d_in[1];
  const int*   Wr = (const int*)d_in[2];
  const int*   Wc = (const int*)d_in[3];
  float* out = (float*)d_out;
  const int nnz = in_sizes[1];

  char* ws = (char*)d_ws;
  const size_t OFF_XT   = 0;                                      // 2 MB
  const size_t OFF_OUTT = OFF_XT   + (size_t)INF * BATCH * 4;     // 2 MB
  const size_t OFF_SVC  = OFF_OUTT + (size_t)OUTF * BATCH * 4;    // nnz*8 = 8 MB
  const size_t OFF_CSR  = OFF_SVC  + (size_t)nnz * 8;             // nnz*8 = 8 MB
  const size_t OFF_SEG  = OFF_CSR  + (size_t)nnz * 8;             // NB*(OUTF+1)*4 ~ 4.2 MB
  const size_t OFF_CNT  = OFF_SEG  + (size_t)NB * (OUTF + 1) * 4; // 16 KB
  const size_t OFF_RP   = OFF_CNT  + (size_t)OUTF * 4;            // 16.4 KB
  const size_t NEEDED   = OFF_RP   + (size_t)(OUTF + 4) * 4;      // ~24.3 MB

  if (ws_size < NEEDED) {
    hipMemsetAsync(d_out, 0, (size_t)out_size * 4, stream);
    k_fallback<<<dim3((nnz + 255) / 256), dim3(256), 0, stream>>>(X, Wv, Wr, Wc, nnz, out);
    return;
  }

  float* XT      = (float*)(ws + OFF_XT);
  float* outT    = (float*)(ws + OFF_OUTT);
  int2*  svc     = (int2*)(ws + OFF_SVC);
  int2*  csr     = (int2*)(ws + OFF_CSR);
  int*   segStart= (int*)(ws + OFF_SEG);
  int*   count   = (int*)(ws + OFF_CNT);
  int*   rowPtr  = (int*)(ws + OFF_RP);

  const int chunk = (nnz + NB - 1) / NB;  // 4096

  k_transpose32<<<dim3(INF / 32, BATCH / 32), dim3(32, 32), 0, stream>>>(X, XT, BATCH, INF);
  k_localsort<<<dim3(NB), dim3(SORT_T), 0, stream>>>(Wv, Wr, Wc, nnz, chunk, svc, segStart);
  k_counts<<<dim3(OUTF / 256), dim3(256), 0, stream>>>(segStart, count);
  k_scan<<<dim3(1), dim3(1024), 0, stream>>>(count, rowPtr);
  k_repack<<<dim3(OUTF), dim3(64), 0, stream>>>(svc, segStart, rowPtr, csr);
  k_spmm<<<dim3(OUTF), dim3(64), 0, stream>>>(csr, rowPtr, XT, outT);
  k_transpose32<<<dim3(BATCH / 32, OUTF / 32), dim3(32, 32), 0, stream>>>(outT, out, OUTF, BATCH);
}